// Round 1
// 368.843 us; speedup vs baseline: 1.0128x; 1.0128x over previous
//
#include <hip/hip_runtime.h>
#include <stdint.h>

// Problem constants (match reference)
#define BB 64
#define MM 2048
#define DD 512
#define CHUNK 64                       // rows of M per block
#define SPLITS (MM / CHUNK)            // 32
#define TROWS 8                        // rows per LDS tile
#define NT (CHUNK / TROWS)             // 8 tiles per block
#define TILE_FLOATS (TROWS * DD)       // 4096 floats = 16 KiB
#define TILE_BYTES (TILE_FLOATS * 4)   // 16384
#define NBUF 3                         // depth-2 prefetch pipeline

// Async global->LDS, 16B per lane (global_load_lds_dwordx4).
// LDS dest per lane MUST be wave-uniform-base + lane*16 (m104/m108) — our
// linear tid*16 layout satisfies this (no padding).
__device__ __forceinline__ void async_copy16(const void* g, void* l) {
    __builtin_amdgcn_global_load_lds(
        (const __attribute__((address_space(1))) unsigned int*)g,
        (__attribute__((address_space(3))) unsigned int*)l, 16, 0, 0);
}

// Kernel 1: per (b, chunk) block, argmax of squared L2 distance over 64 rows.
//
// T3/T4 structure: 3 LDS buffers, 2 tiles always in flight. Each iteration
// waits with a COUNTED s_waitcnt vmcnt(4) (tile t landed; tile t+1's 4 loads
// per thread stay in flight across the barrier), then immediately issues
// stage(t+2). The memory pipe never drains to 0 until the final tile — unlike
// __syncthreads(), which forces vmcnt(0) and empties the pipe 8x per block.
//
// Buffer-reuse safety: stage(t+2) writes buf (t+2)%3 == (t-1)%3, which was
// last read in compute(t-1). Every wave finished compute(t-1) before arriving
// at barrier(t) (program order), and stage(t+2) is issued after barrier(t)
// exit -> no WAR hazard. WAW on the same LDS bytes: this thread's stage(t-1)
// loads completed at iteration (t-1)'s vmcnt wait.
__global__ __launch_bounds__(256) void dist_argmax_kernel(
    const float* __restrict__ inputs,   // [B, D]
    const float* __restrict__ buffer,   // [B, M, D]
    float* __restrict__ ws_d,           // [B, SPLITS]
    int*   __restrict__ ws_i)           // [B, SPLITS]
{
    __shared__ float lds[NBUF * TILE_FLOATS];   // 48 KiB -> 3 blocks/CU
    __shared__ float sd[4];
    __shared__ int   si[4];

    const int b     = blockIdx.x;
    const int chunk = blockIdx.y;
    const int tid   = threadIdx.x;
    const int lane  = tid & 63;
    const int wave  = tid >> 6;
    const int c     = tid & 31;   // column strip 0..31 (16 floats each)
    const int rit   = tid >> 5;   // row within tile 0..7

    // Query strip for this thread's columns: floats [c*16, c*16+16)
    const float4* q4 = (const float4*)(inputs + (size_t)b * DD + (size_t)c * 16);
    float4 q[4];
    #pragma unroll
    for (int k = 0; k < 4; k++) q[k] = q4[k];

    const char* gbase = (const char*)(buffer + (size_t)b * MM * DD
                                             + (size_t)chunk * CHUNK * DD);
    char* lbase = (char*)lds;

    // Prologue: stage tiles 0 and 1 (8 loads/thread in flight)
    #pragma unroll
    for (int i = 0; i < 4; i++)
        async_copy16(gbase + (size_t)i * 4096 + (size_t)tid * 16,
                     lbase + (size_t)i * 4096 + (size_t)tid * 16);
    #pragma unroll
    for (int i = 0; i < 4; i++)
        async_copy16(gbase + TILE_BYTES + (size_t)i * 4096 + (size_t)tid * 16,
                     lbase + TILE_BYTES + (size_t)i * 4096 + (size_t)tid * 16);

    float best_d = -1.0f;
    int   best_i = 0;

    #pragma unroll
    for (int t = 0; t < NT; t++) {
        // Counted wait: oldest 4 loads (tile t) complete; tile t+1 stays in
        // flight across the barrier. Only the last tile drains to 0.
        // (The initial q-loads are older than all stages, so they're counted
        // first — conservative, never incorrect.)
        if (t < NT - 1) {
            asm volatile("s_waitcnt vmcnt(4)" ::: "memory");
        } else {
            asm volatile("s_waitcnt vmcnt(0)" ::: "memory");
        }
        __builtin_amdgcn_s_barrier();

        // Issue stage(t+2) immediately — in flight across compute(t) AND
        // compute(t+1); waited on two iterations from now.
        if (t + 2 < NT) {
            const char* g = gbase + (size_t)(t + 2) * TILE_BYTES;
            char*       l = lbase + (size_t)((t + 2) % NBUF) * TILE_BYTES;
            #pragma unroll
            for (int i = 0; i < 4; i++)
                async_copy16(g + (size_t)i * 4096 + (size_t)tid * 16,
                             l + (size_t)i * 4096 + (size_t)tid * 16);
        }

        // compute tile t (reads buf t%3 — disjoint from both in-flight tiles)
        const float* L = lds + (size_t)(t % NBUF) * TILE_FLOATS
                             + (size_t)rit * DD + (size_t)c * 16;
        float s = 0.0f;
        #pragma unroll
        for (int k0 = 0; k0 < 4; k0++) {
            const int k = (k0 + (c >> 1)) & 3;   // bank stagger; covers k 0..3
            float4 v = *(const float4*)(L + k * 4);
            float dx;
            dx = v.x - q[k].x; s = fmaf(dx, dx, s);
            dx = v.y - q[k].y; s = fmaf(dx, dx, s);
            dx = v.z - q[k].z; s = fmaf(dx, dx, s);
            dx = v.w - q[k].w; s = fmaf(dx, dx, s);
        }
        // one butterfly reduces all 8 rows: each row occupies a 32-lane half
        #pragma unroll
        for (int off = 1; off < 32; off <<= 1)
            s += __shfl_xor(s, off, 64);

        // per-lane row sequence is ascending in t; strict > = first occurrence
        const int r = chunk * CHUNK + t * TROWS + rit;
        if (s > best_d) { best_d = s; best_i = r; }
    }

    // merge the two 32-lane halves of the wave (tie -> lower index)
    {
        float od = __shfl_xor(best_d, 32, 64);
        int   oi = __shfl_xor(best_i, 32, 64);
        if (od > best_d || (od == best_d && oi < best_i)) {
            best_d = od; best_i = oi;
        }
    }
    if (lane == 0) { sd[wave] = best_d; si[wave] = best_i; }
    __syncthreads();
    if (tid == 0) {
        float bd = sd[0]; int bi = si[0];
        #pragma unroll
        for (int w = 1; w < 4; w++) {
            if (sd[w] > bd || (sd[w] == bd && si[w] < bi)) { bd = sd[w]; bi = si[w]; }
        }
        ws_d[b * SPLITS + chunk] = bd;
        ws_i[b * SPLITS + chunk] = bi;
    }
}

// Kernel 2: reduce the 32 partials per batch row, gather the winning row.
__global__ __launch_bounds__(128) void gather_kernel(
    const float* __restrict__ ws_d,
    const int*   __restrict__ ws_i,
    const float* __restrict__ buffer,
    float*       __restrict__ out)
{
    const int b   = blockIdx.x;
    const int tid = threadIdx.x;
    __shared__ int s_idx;

    if (tid < 64) {
        float d = (tid < SPLITS) ? ws_d[b * SPLITS + tid] : -1.0f;
        int   i = (tid < SPLITS) ? ws_i[b * SPLITS + tid] : 0x7fffffff;
        #pragma unroll
        for (int off = 32; off > 0; off >>= 1) {
            float od = __shfl_down(d, off, 64);
            int   oi = __shfl_down(i, off, 64);
            if (od > d || (od == d && oi < i)) { d = od; i = oi; }
        }
        if (tid == 0) s_idx = i;
    }
    __syncthreads();

    const int idx = s_idx;
    const float4* src = (const float4*)(buffer + ((size_t)b * MM + idx) * DD);
    float4*       dst = (float4*)(out + (size_t)b * DD);
    dst[tid] = src[tid];   // D/4 = 128 float4s, 128 threads
}

extern "C" void kernel_launch(void* const* d_in, const int* in_sizes, int n_in,
                              void* d_out, int out_size, void* d_ws, size_t ws_size,
                              hipStream_t stream) {
    const float* inputs = (const float*)d_in[0];   // [B, D]
    const float* buffer = (const float*)d_in[1];   // [B, M, D]
    float* out  = (float*)d_out;                   // [B, D]
    float* ws_d = (float*)d_ws;                    // [B, SPLITS]
    int*   ws_i = (int*)(ws_d + BB * SPLITS);      // [B, SPLITS]

    dim3 grid(BB, SPLITS);
    dist_argmax_kernel<<<grid, 256, 0, stream>>>(inputs, buffer, ws_d, ws_i);
    gather_kernel<<<BB, 128, 0, stream>>>(ws_d, ws_i, buffer, out);
}